// Round 5
// baseline (3887.146 us; speedup 1.0000x reference)
//
#include <hip/hip_runtime.h>

#define Hh 64
#define Tt 2048
#define Bb 256
#define NL 3

__device__ __forceinline__ float fast_sigmoid(float x) {
    return 1.0f / (1.0f + __expf(-x));
}
__device__ __forceinline__ float fast_tanh(float x) {
    float e = __expf(2.0f * x);
    return 1.0f - 2.0f / (e + 1.0f);
}
__device__ __forceinline__ float fma4(float acc, const float4 a, const float4 b) {
    acc = fmaf(a.x, b.x, acc);
    acc = fmaf(a.y, b.y, acc);
    acc = fmaf(a.z, b.z, acc);
    acc = fmaf(a.w, b.w, acc);
    return acc;
}

#define REPEAT16(M) M(0) M(1) M(2) M(3) M(4) M(5) M(6) M(7) \
                    M(8) M(9) M(10) M(11) M(12) M(13) M(14) M(15)

// One block per batch element, 6 waves = 2 per GRU layer, layers software-
// pipelined with skew 1 (layer l does t = p - l at phase p).
//   s=0: {Wih_r.x, Whh_r.h, Whh_n.h} -> r, u = r*(Whh_n.h + bhn)
//   s=1: {Wih_z.x, Whh_z.h, Wih_n.x} -> z, then n = tanh(axn + u), h_new
// Weights: 48 NAMED float4 (constant indices only -> guaranteed SROA into
// VGPRs; indexed arrays went to scratch in R1/R3/R4: VGPR=88/228/128).
// Layer-2 output staged in lane-private LDS rows, flushed 128B/lane/32 phases.
__global__ __launch_bounds__(384, 1)
void gru_pipe(const float* __restrict__ in, float* __restrict__ out,
              const float* __restrict__ Wih, const float* __restrict__ Whh,
              const float* __restrict__ bih, const float* __restrict__ bhh)
{
    const int b   = blockIdx.x;
    const int tid = threadIdx.x;
    const int w   = tid >> 6;    // wave 0..5
    const int l   = w >> 1;      // layer 0..2
    const int s   = w & 1;       // role within layer
    const int i   = tid & 63;    // hidden unit

    const float* WihL = Wih + (long)l * 192 * 64;
    const float* WhhL = Whh + (long)l * 192 * 64;
    const float4* pa4 = (const float4*)(s ? WihL + (long)(64 + i) * 64 : WihL + (long)i * 64);
    const float4* pb4 = (const float4*)(s ? WhhL + (long)(64 + i) * 64 : WhhL + (long)i * 64);
    const float4* pc4 = (const float4*)(s ? WihL + (long)(128 + i) * 64 : WhhL + (long)(128 + i) * 64);

#define DECLW(k) float4 wa##k, wb##k, wc##k;
    REPEAT16(DECLW)
#undef DECLW
#define LOADW(k) wa##k = pa4[k]; wb##k = pb4[k]; wc##k = pc4[k];
    REPEAT16(LOADW)
#undef LOADW

    const float bA = s ? (bih[l*192 + 64 + i] + bhh[l*192 + 64 + i])
                       : (bih[l*192 + i]      + bhh[l*192 + i]);
    const float bC = s ? bih[l*192 + 128 + i] : bhh[l*192 + 128 + i];

    __shared__ float hbuf[NL][2][Hh];   // per-layer h, double-buffered by parity
    __shared__ float xbuf[2][Hh];       // layer-0 input, double-buffered
    __shared__ float ubuf[NL][Hh];      // r*(Whh_n.h + bhn), s=0 -> s=1
    __shared__ float obuf[Hh][33];      // layer-2 output staging, +1 pad

    const long ib = (long)b * Hh * Tt;  // [B,H,T]

    hbuf[l][0][i] = 0.0f;
    hbuf[l][1][i] = 0.0f;
    float hprev = 0.0f;                  // lives in s=1 lanes
    float xcur = 0.0f, xnext = 0.0f;     // live in wave 4: x prefetch duty
    if (w == 4) {
        xbuf[0][i] = in[ib + (long)i * Tt + 0];
        xcur       = in[ib + (long)i * Tt + 1];
    }
    __syncthreads();

    // loop-invariant LDS source pointers per parity (wave-uniform)
    const float4* xsA = (const float4*)((l == 0) ? xbuf[0] : hbuf[l - 1][0]);
    const float4* xsB = (const float4*)((l == 0) ? xbuf[1] : hbuf[l - 1][1]);
    const float4* hsA = (const float4*)hbuf[l][0];
    const float4* hsB = (const float4*)hbuf[l][1];

    for (int p = 0; p < Tt + NL - 1; ++p) {
        const int rd = p & 1;
        const int t  = p - l;
        const bool act = (t >= 0) && (t < Tt);

        // x prefetch issue at phase top: latency hides under the dot phase
        if (w == 4 && p + 2 < Tt) xnext = in[ib + (long)i * Tt + (p + 2)];

        float accA = bA, accB = 0.0f, accC = bC;
        if (act) {
            const float4* xs4 = rd ? xsB : xsA;
            const float4* hs4 = rd ? hsB : hsA;
            if (s == 0) {
#define DOT0(k) { const float4 xv = xs4[k], hv = hs4[k]; \
                  accA = fma4(accA, wa##k, xv); \
                  accB = fma4(accB, wb##k, hv); \
                  accC = fma4(accC, wc##k, hv); }
                REPEAT16(DOT0)
#undef DOT0
            } else {
#define DOT1(k) { const float4 xv = xs4[k], hv = hs4[k]; \
                  accA = fma4(accA, wa##k, xv); \
                  accB = fma4(accB, wb##k, hv); \
                  accC = fma4(accC, wc##k, xv); }
                REPEAT16(DOT1)
#undef DOT1
            }
            const float g = fast_sigmoid(accA + accB);   // r (s=0) or z (s=1)
            if (s == 0) ubuf[l][i] = g * accC;           // u = r*(Whh_n.h + bhn)
            accA = g;                                    // carry gate across B1
        }
        __syncthreads();   // B1: u visible

        if (act && s == 1) {
            const float n = fast_tanh(accC + ubuf[l][i]);    // accC = Wih_n.x + bxn
            const float hnew = fmaf(accA, hprev - n, n);     // (1-z)*n + z*h
            hprev = hnew;
            hbuf[l][rd ^ 1][i] = hnew;
            if (l == NL - 1) obuf[i][t & 31] = hnew;         // lane-private row
        }
        if (w == 4) {
            if (p + 1 < Tt) xbuf[rd ^ 1][i] = xcur;
            xcur = xnext;
        }
        __syncthreads();   // B2: h/x published for next phase

        // Flush staged output: lane i owns row i entirely (no cross-lane dep).
        // 8 x float4 = one full 128B HBM line per lane, written once.
        if (w == 5 && act && (t & 31) == 31) {
            float4* dst = (float4*)(out + ib + (long)i * Tt + (t - 31));
            const float* src = obuf[i];
#define OFL(k2) dst[k2] = make_float4(src[4*k2], src[4*k2+1], src[4*k2+2], src[4*k2+3]);
            OFL(0) OFL(1) OFL(2) OFL(3) OFL(4) OFL(5) OFL(6) OFL(7)
#undef OFL
        }
    }
}

extern "C" void kernel_launch(void* const* d_in, const int* in_sizes, int n_in,
                              void* d_out, int out_size, void* d_ws, size_t ws_size,
                              hipStream_t stream) {
    const float* x   = (const float*)d_in[0];   // [B, H, T]
    const float* Wih = (const float*)d_in[1];   // [3, 192, 64]
    const float* Whh = (const float*)d_in[2];   // [3, 192, 64]
    const float* bih = (const float*)d_in[3];   // [3, 192]
    const float* bhh = (const float*)d_in[4];   // [3, 192]
    float* out = (float*)d_out;                 // [B, H, T]

    gru_pipe<<<Bb, 384, 0, stream>>>(x, out, Wih, Whh, bih, bhh);
}

// Round 6
// 3881.275 us; speedup vs baseline: 1.0015x; 1.0015x over previous
//
#include <hip/hip_runtime.h>

#define Hh 64
#define Tt 2048
#define Bb 256
#define NL 3

__device__ __forceinline__ float fast_sigmoid(float x) {
    return 1.0f / (1.0f + __expf(-x));
}
__device__ __forceinline__ float fast_tanh(float x) {
    float e = __expf(2.0f * x);
    return 1.0f - 2.0f / (e + 1.0f);
}
__device__ __forceinline__ float fma4(float acc, const float4 a, const float4 b) {
    acc = fmaf(a.x, b.x, acc);
    acc = fmaf(a.y, b.y, acc);
    acc = fmaf(a.z, b.z, acc);
    acc = fmaf(a.w, b.w, acc);
    return acc;
}

#define REPEAT16(M) M(0) M(1) M(2) M(3) M(4) M(5) M(6) M(7) \
                    M(8) M(9) M(10) M(11) M(12) M(13) M(14) M(15)

// One block per batch element, 6 waves = 2 per GRU layer, layers software-
// pipelined with skew 1 (layer l does t = p - l at phase p).
//   s=0: {Wih_r.x, Whh_r.h, Whh_n.h} -> r, u = r*(Whh_n.h + bhn)
//   s=1: {Wih_z.x, Whh_z.h, Wih_n.x} -> z, then n = tanh(axn + u), h_new
// Weights: 48 NAMED float4 per lane (192 regs). R5 showed the backend caps
// VGPR at 128 (4-waves/EU occupancy heuristic) and rematerializes weight
// loads from L2 every phase -> L2-BW-bound. amdgpu_waves_per_eu(2) sets the
// budget to 512/2 = 256 VGPRs: weights stay register-resident, and a 6-wave
// block still fits (busiest SIMD hosts exactly 2 waves).
__global__ __launch_bounds__(384)
__attribute__((amdgpu_waves_per_eu(2)))
void gru_pipe(const float* __restrict__ in, float* __restrict__ out,
              const float* __restrict__ Wih, const float* __restrict__ Whh,
              const float* __restrict__ bih, const float* __restrict__ bhh)
{
    const int b   = blockIdx.x;
    const int tid = threadIdx.x;
    const int w   = tid >> 6;    // wave 0..5
    const int l   = w >> 1;      // layer 0..2
    const int s   = w & 1;       // role within layer
    const int i   = tid & 63;    // hidden unit

    const float* WihL = Wih + (long)l * 192 * 64;
    const float* WhhL = Whh + (long)l * 192 * 64;
    const float4* pa4 = (const float4*)(s ? WihL + (long)(64 + i) * 64 : WihL + (long)i * 64);
    const float4* pb4 = (const float4*)(s ? WhhL + (long)(64 + i) * 64 : WhhL + (long)i * 64);
    const float4* pc4 = (const float4*)(s ? WihL + (long)(128 + i) * 64 : WhhL + (long)(128 + i) * 64);

#define DECLW(k) float4 wa##k, wb##k, wc##k;
    REPEAT16(DECLW)
#undef DECLW
#define LOADW(k) wa##k = pa4[k]; wb##k = pb4[k]; wc##k = pc4[k];
    REPEAT16(LOADW)
#undef LOADW

    const float bA = s ? (bih[l*192 + 64 + i] + bhh[l*192 + 64 + i])
                       : (bih[l*192 + i]      + bhh[l*192 + i]);
    const float bC = s ? bih[l*192 + 128 + i] : bhh[l*192 + 128 + i];

    __shared__ float hbuf[NL][2][Hh];   // per-layer h, double-buffered by parity
    __shared__ float xbuf[2][Hh];       // layer-0 input, double-buffered
    __shared__ float ubuf[NL][Hh];      // r*(Whh_n.h + bhn), s=0 -> s=1
    __shared__ float obuf[Hh][33];      // layer-2 output staging, +1 pad

    const long ib = (long)b * Hh * Tt;  // [B,H,T]

    hbuf[l][0][i] = 0.0f;
    hbuf[l][1][i] = 0.0f;
    float hprev = 0.0f;                  // lives in s=1 lanes
    float xcur = 0.0f, xnext = 0.0f;     // live in wave 4: x prefetch duty
    if (w == 4) {
        xbuf[0][i] = in[ib + (long)i * Tt + 0];
        xcur       = in[ib + (long)i * Tt + 1];
    }
    __syncthreads();

    // loop-invariant LDS source pointers per parity (wave-uniform)
    const float4* xsA = (const float4*)((l == 0) ? xbuf[0] : hbuf[l - 1][0]);
    const float4* xsB = (const float4*)((l == 0) ? xbuf[1] : hbuf[l - 1][1]);
    const float4* hsA = (const float4*)hbuf[l][0];
    const float4* hsB = (const float4*)hbuf[l][1];

    for (int p = 0; p < Tt + NL - 1; ++p) {
        const int rd = p & 1;
        const int t  = p - l;
        const bool act = (t >= 0) && (t < Tt);

        // x prefetch issue at phase top: latency hides under the dot phase
        if (w == 4 && p + 2 < Tt) xnext = in[ib + (long)i * Tt + (p + 2)];

        float accA = bA, accB = 0.0f, accC = bC;
        if (act) {
            const float4* xs4 = rd ? xsB : xsA;
            const float4* hs4 = rd ? hsB : hsA;
            if (s == 0) {
#define DOT0(k) { const float4 xv = xs4[k], hv = hs4[k]; \
                  accA = fma4(accA, wa##k, xv); \
                  accB = fma4(accB, wb##k, hv); \
                  accC = fma4(accC, wc##k, hv); }
                REPEAT16(DOT0)
#undef DOT0
            } else {
#define DOT1(k) { const float4 xv = xs4[k], hv = hs4[k]; \
                  accA = fma4(accA, wa##k, xv); \
                  accB = fma4(accB, wb##k, hv); \
                  accC = fma4(accC, wc##k, xv); }
                REPEAT16(DOT1)
#undef DOT1
            }
            const float g = fast_sigmoid(accA + accB);   // r (s=0) or z (s=1)
            if (s == 0) ubuf[l][i] = g * accC;           // u = r*(Whh_n.h + bhn)
            accA = g;                                    // carry gate across B1
        }
        __syncthreads();   // B1: u visible

        if (act && s == 1) {
            const float n = fast_tanh(accC + ubuf[l][i]);    // accC = Wih_n.x + bxn
            const float hnew = fmaf(accA, hprev - n, n);     // (1-z)*n + z*h
            hprev = hnew;
            hbuf[l][rd ^ 1][i] = hnew;
            if (l == NL - 1) obuf[i][t & 31] = hnew;         // lane-private row
        }
        if (w == 4) {
            if (p + 1 < Tt) xbuf[rd ^ 1][i] = xcur;
            xcur = xnext;
        }
        __syncthreads();   // B2: h/x published for next phase

        // Flush staged output: lane i owns row i entirely (no cross-lane dep).
        // 8 x float4 = one full 128B HBM line per lane, written once.
        if (w == 5 && act && (t & 31) == 31) {
            float4* dst = (float4*)(out + ib + (long)i * Tt + (t - 31));
            const float* src = obuf[i];
#define OFL(k2) dst[k2] = make_float4(src[4*k2], src[4*k2+1], src[4*k2+2], src[4*k2+3]);
            OFL(0) OFL(1) OFL(2) OFL(3) OFL(4) OFL(5) OFL(6) OFL(7)
#undef OFL
        }
    }
}

extern "C" void kernel_launch(void* const* d_in, const int* in_sizes, int n_in,
                              void* d_out, int out_size, void* d_ws, size_t ws_size,
                              hipStream_t stream) {
    const float* x   = (const float*)d_in[0];   // [B, H, T]
    const float* Wih = (const float*)d_in[1];   // [3, 192, 64]
    const float* Whh = (const float*)d_in[2];   // [3, 192, 64]
    const float* bih = (const float*)d_in[3];   // [3, 192]
    const float* bhh = (const float*)d_in[4];   // [3, 192]
    float* out = (float*)d_out;                 // [B, H, T]

    gru_pipe<<<Bb, 384, 0, stream>>>(x, out, Wih, Whh, bih, bhh);
}

// Round 7
// 3515.712 us; speedup vs baseline: 1.1056x; 1.1040x over previous
//
#include <hip/hip_runtime.h>

#define Hh 64
#define Tt 2048
#define Bb 256
#define NL 3

typedef float f4 __attribute__((ext_vector_type(4)));

__device__ __forceinline__ float fast_sigmoid(float x) {
    return 1.0f / (1.0f + __expf(-x));
}
__device__ __forceinline__ float fast_tanh(float x) {
    float e = __expf(2.0f * x);
    return 1.0f - 2.0f / (e + 1.0f);
}
__device__ __forceinline__ float fma4(float acc, f4 a, f4 b) {
    acc = fmaf(a[0], b[0], acc);
    acc = fmaf(a[1], b[1], acc);
    acc = fmaf(a[2], b[2], acc);
    acc = fmaf(a[3], b[3], acc);
    return acc;
}

#define REP8(M) M(0) M(1) M(2) M(3) M(4) M(5) M(6) M(7)

// One block per batch element, 12 waves = 4 per layer. Layers software-
// pipelined with skew 1 (layer l does t = p - l at phase p).
// Wave (l, s, uh): role s (0: r-gate + h-side n-dot -> u ; 1: z-gate + x-side
// n-dot -> h update), unit-half uh. Lane (kh, jj): unit j = uh*32+jj, k-half kh.
// Each lane holds 3 HALF-rows = 96 weight floats (24 quads) -> fits the
// backend's hard 128-VGPR choice (R4/R5/R6 all refused >128 and re-streamed
// 192-float sets from L2 at the 37 TB/s ceiling). K-partials reduce
// intra-wave via shfl_xor(32): no extra barrier. 2 barriers/phase.
__global__ __launch_bounds__(768, 3)
void gru_pipe(const float* __restrict__ in, float* __restrict__ out,
              const float* __restrict__ Wih, const float* __restrict__ Whh,
              const float* __restrict__ bih, const float* __restrict__ bhh)
{
    const int b   = blockIdx.x;
    const int tid = threadIdx.x;
    const int w   = tid >> 6;        // 0..11
    const int l   = w >> 2;          // layer 0..2
    const int s   = (w >> 1) & 1;    // role
    const int uh  = w & 1;           // unit half
    const int ln  = tid & 63;
    const int kh  = ln >> 5;         // k half
    const int jj  = ln & 31;
    const int j   = uh * 32 + jj;    // hidden unit

    const float* WihL = Wih + (long)l * 192 * 64;
    const float* WhhL = Whh + (long)l * 192 * 64;
    const int gA = s ? 64 + j : j;                    // r-row or z-row (same idx for ih/hh)
    const f4* pa = (const f4*)(WihL + (long)gA * 64 + kh * 32);
    const f4* pb = (const f4*)(WhhL + (long)gA * 64 + kh * 32);
    const f4* pc = (const f4*)((s ? WihL : WhhL) + (long)(128 + j) * 64 + kh * 32);

#define DECLW(k) f4 a##k = pa[k]; f4 b##k = pb[k]; f4 c##k = pc[k];
    REP8(DECLW)
#undef DECLW

    // bias seeded only in kh==0 lanes (shfl-sum would double-count otherwise)
    float bA = 0.0f, bC = 0.0f;
    if (kh == 0) {
        bA = bih[l*192 + gA] + bhh[l*192 + gA];
        bC = s ? bih[l*192 + 128 + j] : bhh[l*192 + 128 + j];
    }

    __shared__ float hbuf[NL][2][Hh];   // per-layer h, double-buffered by parity
    __shared__ float xbuf[2][Hh];       // layer-0 input, double-buffered
    __shared__ float ubuf[NL][Hh];      // r*(Whh_n.h + bhn), s=0 -> s=1
    __shared__ float obuf[2][32][33];   // layer-2 out staging per s=1 wave, +1 pad

    const long ib = (long)b * Hh * Tt;  // [B,H,T]

    if (tid < NL * 2 * Hh) ((float*)hbuf)[tid] = 0.0f;
    float hprev = 0.0f;                 // s=1 lanes (both kh halves, redundant)
    float xcur = 0.0f, xnext = 0.0f;    // wave 8: x prefetch duty
    if (w == 8) {
        xbuf[0][ln] = in[ib + (long)ln * Tt + 0];
        xcur        = in[ib + (long)ln * Tt + 1];
    }
    __syncthreads();

    for (int p = 0; p < Tt + NL - 1; ++p) {
        const int rd = p & 1;
        const int t  = p - l;
        const bool act = (t >= 0) && (t < Tt);

        // Forbid rematerialization: weights are opaque register values.
#define KEEP(k) asm volatile("" : "+v"(a##k), "+v"(b##k), "+v"(c##k));
        REP8(KEEP)
#undef KEEP

        if (w == 8 && p + 2 < Tt) xnext = in[ib + (long)ln * Tt + (p + 2)];

        float accA = bA, accB = 0.0f, accC = bC;
        float zg = 0.0f;
        if (act) {
            const f4* xs4 = (const f4*)((l == 0) ? xbuf[rd] : hbuf[l - 1][rd]) + kh * 8;
            const f4* hs4 = (const f4*)hbuf[l][rd] + kh * 8;
            if (s == 0) {
#define D0(k) { const f4 xv = xs4[k], hv = hs4[k]; \
                accA = fma4(accA, a##k, xv); \
                accB = fma4(accB, b##k, hv); \
                accC = fma4(accC, c##k, hv); }
                REP8(D0)
#undef D0
            } else {
#define D1(k) { const f4 xv = xs4[k], hv = hs4[k]; \
                accA = fma4(accA, a##k, xv); \
                accB = fma4(accB, b##k, hv); \
                accC = fma4(accC, c##k, xv); }
                REP8(D1)
#undef D1
            }
            // cross k-half reduction (intra-wave, lane ^ 32)
            accA += __shfl_xor(accA, 32);
            accB += __shfl_xor(accB, 32);
            accC += __shfl_xor(accC, 32);
            const float g = fast_sigmoid(accA + accB);   // r (s=0) or z (s=1)
            if (s == 0) {
                if (kh == 0) ubuf[l][j] = g * accC;      // u = r*(Whh_n.h + bhn)
            }
            zg = g;
        }
        __syncthreads();   // B1: u visible

        if (act && s == 1) {
            const float n = fast_tanh(accC + ubuf[l][j]);   // accC = Wih_n.x + bxn
            const float hnew = fmaf(zg, hprev - n, n);      // (1-z)*n + z*h
            hprev = hnew;
            if (kh == 0) {
                hbuf[l][rd ^ 1][j] = hnew;
                if (l == NL - 1) obuf[uh][jj][t & 31] = hnew;
            }
        }
        if (w == 8) {
            if (p + 1 < Tt) xbuf[rd ^ 1][ln] = xcur;
            xcur = xnext;
        }
        __syncthreads();   // B2: h/x published for next phase

        // Flush staged output every 32 phases. Wave 10 -> units 0-31,
        // wave 11 -> units 32-63 (same wave that wrote: no race).
        // Lane (kh,jj): floats [kh*16, kh*16+16) of unit j's row -> 4x dwordx4,
        // 128B per row written contiguously, once.
        if ((w >> 1) == 5 && act && (t & 31) == 31) {
            const float* srow = obuf[uh][jj] + kh * 16;
            float4* dst = (float4*)(out + ib + (long)j * Tt + (t - 31) + kh * 16);
            dst[0] = make_float4(srow[0],  srow[1],  srow[2],  srow[3]);
            dst[1] = make_float4(srow[4],  srow[5],  srow[6],  srow[7]);
            dst[2] = make_float4(srow[8],  srow[9],  srow[10], srow[11]);
            dst[3] = make_float4(srow[12], srow[13], srow[14], srow[15]);
        }
    }
}

extern "C" void kernel_launch(void* const* d_in, const int* in_sizes, int n_in,
                              void* d_out, int out_size, void* d_ws, size_t ws_size,
                              hipStream_t stream) {
    const float* x   = (const float*)d_in[0];   // [B, H, T]
    const float* Wih = (const float*)d_in[1];   // [3, 192, 64]
    const float* Whh = (const float*)d_in[2];   // [3, 192, 64]
    const float* bih = (const float*)d_in[3];   // [3, 192]
    const float* bhh = (const float*)d_in[4];   // [3, 192]
    float* out = (float*)d_out;                 // [B, H, T]

    gru_pipe<<<Bb, 768, 0, stream>>>(x, out, Wih, Whh, bih, bhh);
}

// Round 8
// 2953.271 us; speedup vs baseline: 1.3162x; 1.1904x over previous
//
#include <hip/hip_runtime.h>

#define Hh 64
#define Tt 2048
#define Bb 256
#define NL 3

typedef float f4 __attribute__((ext_vector_type(4)));

__device__ __forceinline__ float fast_sigmoid(float x) {
    return 1.0f / (1.0f + __expf(-x));
}
__device__ __forceinline__ float fast_tanh(float x) {
    float e = __expf(2.0f * x);
    return 1.0f - 2.0f / (e + 1.0f);
}
__device__ __forceinline__ float fma4(float acc, f4 a, f4 b) {
    acc = fmaf(a[0], b[0], acc);
    acc = fmaf(a[1], b[1], acc);
    acc = fmaf(a[2], b[2], acc);
    acc = fmaf(a[3], b[3], acc);
    return acc;
}

#define REP8(M) M(0) M(1) M(2) M(3) M(4) M(5) M(6) M(7)

// One block per batch element, 12 waves = 4 per layer, layers pipelined with
// skew 1 (layer l does t = p - l at phase p). Wave (l, s, uh); lane (kh, jj).
// Each lane: 3 half-rows = 96 weight floats; K-partials reduce via shfl_xor(32).
//
// R3-R7 lesson: invariant weight loads get REMATERIALIZED into the loop by the
// scheduler to hit its occupancy target (2 blocks/CU from 11KB LDS -> 6 waves/EU
// -> 84-128 VGPR cap), re-streaming ~300KB/CU/phase from L2 = 4900 cyc/phase
// (the whole 3.5-4.2ms). The grid is 256 blocks on 256 CUs: that second block
// NEVER exists. Fix: pad static LDS to ~95KB so 1 block/CU is the compiler's
// own conclusion -> 3 waves/EU -> 168-reg budget -> weights stay resident.
__global__ __launch_bounds__(768, 3)
void gru_pipe(const float* __restrict__ in, float* __restrict__ out,
              const float* __restrict__ Wih, const float* __restrict__ Whh,
              const float* __restrict__ bih, const float* __restrict__ bhh)
{
    const int b   = blockIdx.x;
    const int tid = threadIdx.x;
    const int w   = tid >> 6;        // 0..11
    const int l   = w >> 2;          // layer 0..2
    const int s   = (w >> 1) & 1;    // role
    const int uh  = w & 1;           // unit half
    const int ln  = tid & 63;
    const int kh  = ln >> 5;         // k half
    const int jj  = ln & 31;
    const int j   = uh * 32 + jj;    // hidden unit

    const float* WihL = Wih + (long)l * 192 * 64;
    const float* WhhL = Whh + (long)l * 192 * 64;
    const int gA = s ? 64 + j : j;
    const f4* pa = (const f4*)(WihL + (long)gA * 64 + kh * 32);
    const f4* pb = (const f4*)(WhhL + (long)gA * 64 + kh * 32);
    const f4* pc = (const f4*)((s ? WihL : WhhL) + (long)(128 + j) * 64 + kh * 32);

#define DECLW(k) f4 a##k = pa[k]; f4 b##k = pb[k]; f4 c##k = pc[k];
    REP8(DECLW)
#undef DECLW

    float bA = 0.0f, bC = 0.0f;
    if (kh == 0) {
        bA = bih[l*192 + gA] + bhh[l*192 + gA];
        bC = s ? bih[l*192 + 128 + j] : bhh[l*192 + 128 + j];
    }

    __shared__ float hbuf[NL][2][Hh];   // per-layer h, double-buffered by parity
    __shared__ float xbuf[2][Hh];       // layer-0 input, double-buffered
    __shared__ float ubuf[NL][Hh];      // r*(Whh_n.h + bhn), s=0 -> s=1
    __shared__ float obuf[2][32][33];   // layer-2 out staging, +1 pad
    __shared__ float ldspad[21504];     // 84KB occupancy pad: forces 1 block/CU
                                        // in the COMPILER's model (see header)

    const long ib = (long)b * Hh * Tt;  // [B,H,T]

    if (tid < NL * 2 * Hh) ((float*)hbuf)[tid] = 0.0f;
    float hprev = 0.0f;
    float xcur = 0.0f, xnext = 0.0f;    // wave 8: x prefetch duty
    if (w == 8) {
        xbuf[0][ln] = in[ib + (long)ln * Tt + 0];
        xcur        = in[ib + (long)ln * Tt + 1];
    }
    __syncthreads();

    for (int p = 0; p < Tt + NL - 1; ++p) {
        const int rd = p & 1;
        const int t  = p - l;
        const bool act = (t >= 0) && (t < Tt);

        if (w == 8 && p + 2 < Tt) xnext = in[ib + (long)ln * Tt + (p + 2)];

        float accA = bA, accB = 0.0f, accC = bC;
        float zg = 0.0f;
        if (act) {
            const f4* xs4 = (const f4*)((l == 0) ? xbuf[rd] : hbuf[l - 1][rd]) + kh * 8;
            const f4* hs4 = (const f4*)hbuf[l][rd] + kh * 8;
            if (s == 0) {
#define D0(k) { const f4 xv = xs4[k], hv = hs4[k]; \
                accA = fma4(accA, a##k, xv); \
                accB = fma4(accB, b##k, hv); \
                accC = fma4(accC, c##k, hv); }
                REP8(D0)
#undef D0
            } else {
#define D1(k) { const f4 xv = xs4[k], hv = hs4[k]; \
                accA = fma4(accA, a##k, xv); \
                accB = fma4(accB, b##k, hv); \
                accC = fma4(accC, c##k, xv); }
                REP8(D1)
#undef D1
            }
            accA += __shfl_xor(accA, 32);
            accB += __shfl_xor(accB, 32);
            accC += __shfl_xor(accC, 32);
            const float g = fast_sigmoid(accA + accB);   // r (s=0) or z (s=1)
            if (s == 0) {
                if (kh == 0) ubuf[l][j] = g * accC;      // u = r*(Whh_n.h + bhn)
            }
            zg = g;
        }
        __syncthreads();   // B1: u visible

        if (act && s == 1) {
            const float n = fast_tanh(accC + ubuf[l][j]);   // accC = Wih_n.x + bxn
            const float hnew = fmaf(zg, hprev - n, n);      // (1-z)*n + z*h
            hprev = hnew;
            if (kh == 0) {
                hbuf[l][rd ^ 1][j] = hnew;
                if (l == NL - 1) obuf[uh][jj][t & 31] = hnew;
            }
        }
        if (w == 8) {
            if (p + 1 < Tt) xbuf[rd ^ 1][ln] = xcur;
            xcur = xnext;
        }
        __syncthreads();   // B2: h/x published for next phase

        // Flush staged output every 32 phases (waves 10/11, the obuf writers).
        if ((w >> 1) == 5 && act && (t & 31) == 31) {
            const float* srow = obuf[uh][jj] + kh * 16;
            float4* dst = (float4*)(out + ib + (long)j * Tt + (t - 31) + kh * 16);
            dst[0] = make_float4(srow[0],  srow[1],  srow[2],  srow[3]);
            dst[1] = make_float4(srow[4],  srow[5],  srow[6],  srow[7]);
            dst[2] = make_float4(srow[8],  srow[9],  srow[10], srow[11]);
            dst[3] = make_float4(srow[12], srow[13], srow[14], srow[15]);
        }
    }

    // Keep ldspad referenced so it isn't eliminated; bih values are in
    // (-0.125, 0.125) so this never executes, but the compiler can't prove it.
    if (bih[0] > 1.0e30f) out[ib] = ldspad[tid] + ldspad[tid + 10000];
}

extern "C" void kernel_launch(void* const* d_in, const int* in_sizes, int n_in,
                              void* d_out, int out_size, void* d_ws, size_t ws_size,
                              hipStream_t stream) {
    const float* x   = (const float*)d_in[0];   // [B, H, T]
    const float* Wih = (const float*)d_in[1];   // [3, 192, 64]
    const float* Whh = (const float*)d_in[2];   // [3, 192, 64]
    const float* bih = (const float*)d_in[3];   // [3, 192]
    const float* bhh = (const float*)d_in[4];   // [3, 192]
    float* out = (float*)d_out;                 // [B, H, T]

    gru_pipe<<<Bb, 768, 0, stream>>>(x, out, Wih, Whh, bih, bhh);
}

// Round 9
// 2886.057 us; speedup vs baseline: 1.3469x; 1.0233x over previous
//
#include <hip/hip_runtime.h>

#define Hh 64
#define Tt 2048
#define Bb 256
#define NL 3

typedef float f4 __attribute__((ext_vector_type(4)));

__device__ __forceinline__ float fast_sigmoid(float x) {
    return 1.0f / (1.0f + __expf(-x));
}
__device__ __forceinline__ float fast_tanh(float x) {
    float e = __expf(2.0f * x);
    return 1.0f - 2.0f / (e + 1.0f);
}
__device__ __forceinline__ float fma4(float acc, f4 a, f4 b) {
    acc = fmaf(a[0], b[0], acc);
    acc = fmaf(a[1], b[1], acc);
    acc = fmaf(a[2], b[2], acc);
    acc = fmaf(a[3], b[3], acc);
    return acc;
}

#define REP8(M) M(0) M(1) M(2) M(3) M(4) M(5) M(6) M(7)

// One block per batch element, 12 waves = 4 per layer, layers pipelined with
// skew 1 (layer l does t = p - l at phase p). Wave (l, s, uh); lane (kh, jj).
// Each lane: 3 half-rows = 96 weight floats; K-partials reduce via shfl_xor(32).
//
// R3-R8 lesson: the register allocator targets 2 blocks/CU occupancy (6
// waves/EU -> 84-reg budget) and REMATERIALIZES the invariant weight loads
// into the loop, re-streaming ~300KB/block/phase from L2 (~3900 cyc/phase).
// The second block never exists (grid = 256 = #CUs). Two fixes, both pinning
// the occupancy target to 3 waves/EU (budget ~170 regs):
//   1. amdgpu_waves_per_eu(3,3): max=3 clamps the allocator target (R6's
//      min-only (2) was just a floor -- satisfied by its 4-waves choice).
//   2. LDS padded to ~88KB AND actually written (R8's pad was read-only ->
//      undef -> whole array DCE'd, LDS_Block_Size stayed 11264).
__global__
__attribute__((amdgpu_flat_work_group_size(768, 768)))
__attribute__((amdgpu_waves_per_eu(3, 3)))
void gru_pipe(const float* __restrict__ in, float* __restrict__ out,
              const float* __restrict__ Wih, const float* __restrict__ Whh,
              const float* __restrict__ bih, const float* __restrict__ bhh)
{
    const int b   = blockIdx.x;
    const int tid = threadIdx.x;
    const int w   = tid >> 6;        // 0..11
    const int l   = w >> 2;          // layer 0..2
    const int s   = (w >> 1) & 1;    // role
    const int uh  = w & 1;           // unit half
    const int ln  = tid & 63;
    const int kh  = ln >> 5;         // k half
    const int jj  = ln & 31;
    const int j   = uh * 32 + jj;    // hidden unit

    const float* WihL = Wih + (long)l * 192 * 64;
    const float* WhhL = Whh + (long)l * 192 * 64;
    const int gA = s ? 64 + j : j;
    const f4* pa = (const f4*)(WihL + (long)gA * 64 + kh * 32);
    const f4* pb = (const f4*)(WhhL + (long)gA * 64 + kh * 32);
    const f4* pc = (const f4*)((s ? WihL : WhhL) + (long)(128 + j) * 64 + kh * 32);

#define DECLW(k) f4 a##k = pa[k]; f4 b##k = pb[k]; f4 c##k = pc[k];
    REP8(DECLW)
#undef DECLW

    float bA = 0.0f, bC = 0.0f;
    if (kh == 0) {
        bA = bih[l*192 + gA] + bhh[l*192 + gA];
        bC = s ? bih[l*192 + 128 + j] : bhh[l*192 + 128 + j];
    }

    __shared__ float hbuf[NL][2][Hh];   // per-layer h, double-buffered by parity
    __shared__ float xbuf[2][Hh];       // layer-0 input, double-buffered
    __shared__ float ubuf[NL][Hh];      // r*(Whh_n.h + bhn), s=0 -> s=1
    __shared__ float obuf[2][32][33];   // layer-2 out staging, +1 pad
    __shared__ float ldspad[19456];     // ~76KB pad -> ~88KB total: 1 block/CU
                                        // in the compiler's occupancy model

    const long ib = (long)b * Hh * Tt;  // [B,H,T]

    if (tid < NL * 2 * Hh) ((float*)hbuf)[tid] = 0.0f;
    float hprev = 0.0f;
    float xcur = 0.0f, xnext = 0.0f;    // wave 8: x prefetch duty
    if (w == 8) {
        xbuf[0][ln] = in[ib + (long)ln * Tt + 0];
        xcur        = in[ib + (long)ln * Tt + 1];
    }
    __syncthreads();

    for (int p = 0; p < Tt + NL - 1; ++p) {
        const int rd = p & 1;
        const int t  = p - l;
        const bool act = (t >= 0) && (t < Tt);

        if (w == 8 && p + 2 < Tt) xnext = in[ib + (long)ln * Tt + (p + 2)];

        float accA = bA, accB = 0.0f, accC = bC;
        float zg = 0.0f;
        if (act) {
            const f4* xs4 = (const f4*)((l == 0) ? xbuf[rd] : hbuf[l - 1][rd]) + kh * 8;
            const f4* hs4 = (const f4*)hbuf[l][rd] + kh * 8;
            if (s == 0) {
#define D0(k) { const f4 xv = xs4[k], hv = hs4[k]; \
                accA = fma4(accA, a##k, xv); \
                accB = fma4(accB, b##k, hv); \
                accC = fma4(accC, c##k, hv); }
                REP8(D0)
#undef D0
            } else {
#define D1(k) { const f4 xv = xs4[k], hv = hs4[k]; \
                accA = fma4(accA, a##k, xv); \
                accB = fma4(accB, b##k, hv); \
                accC = fma4(accC, c##k, xv); }
                REP8(D1)
#undef D1
            }
            accA += __shfl_xor(accA, 32);
            accB += __shfl_xor(accB, 32);
            accC += __shfl_xor(accC, 32);
            const float g = fast_sigmoid(accA + accB);   // r (s=0) or z (s=1)
            if (s == 0) {
                if (kh == 0) ubuf[l][j] = g * accC;      // u = r*(Whh_n.h + bhn)
            }
            zg = g;
        }
        __syncthreads();   // B1: u visible

        if (act && s == 1) {
            const float n = fast_tanh(accC + ubuf[l][j]);   // accC = Wih_n.x + bxn
            const float hnew = fmaf(zg, hprev - n, n);      // (1-z)*n + z*h
            hprev = hnew;
            if (kh == 0) {
                hbuf[l][rd ^ 1][j] = hnew;
                if (l == NL - 1) obuf[uh][jj][t & 31] = hnew;
            }
        }
        if (w == 8) {
            if (p + 1 < Tt) xbuf[rd ^ 1][ln] = xcur;
            xcur = xnext;
        }
        __syncthreads();   // B2: h/x published for next phase

        // Flush staged output every 32 phases (waves 10/11, the obuf writers).
        if ((w >> 1) == 5 && act && (t & 31) == 31) {
            const float* srow = obuf[uh][jj] + kh * 16;
            float4* dst = (float4*)(out + ib + (long)j * Tt + (t - 31) + kh * 16);
            dst[0] = make_float4(srow[0],  srow[1],  srow[2],  srow[3]);
            dst[1] = make_float4(srow[4],  srow[5],  srow[6],  srow[7]);
            dst[2] = make_float4(srow[8],  srow[9],  srow[10], srow[11]);
            dst[3] = make_float4(srow[12], srow[13], srow[14], srow[15]);
        }
    }

    // Keep ldspad ALIVE: write before read (R8's read-only pad was undef and
    // the array was deleted). bih ~ (-0.125,0.125) so this never executes at
    // runtime, but the compiler cannot prove that.
    if (bih[0] > 1.0e30f) {
        ldspad[tid] = bih[1];
        ldspad[tid + 4096] = bhh[1];
        __syncthreads();
        out[ib] = ldspad[tid ^ 1] + ldspad[(tid ^ 1) + 4096] + ldspad[tid + 10000];
    }
}

extern "C" void kernel_launch(void* const* d_in, const int* in_sizes, int n_in,
                              void* d_out, int out_size, void* d_ws, size_t ws_size,
                              hipStream_t stream) {
    const float* x   = (const float*)d_in[0];   // [B, H, T]
    const float* Wih = (const float*)d_in[1];   // [3, 192, 64]
    const float* Whh = (const float*)d_in[2];   // [3, 192, 64]
    const float* bih = (const float*)d_in[3];   // [3, 192]
    const float* bhh = (const float*)d_in[4];   // [3, 192]
    float* out = (float*)d_out;                 // [B, H, T]

    gru_pipe<<<Bb, 768, 0, stream>>>(x, out, Wih, Whh, bih, bhh);
}

// Round 10
// 2854.466 us; speedup vs baseline: 1.3618x; 1.0111x over previous
//
#include <hip/hip_runtime.h>

#define Hh 64
#define Tt 2048
#define Bb 256
#define NL 3

typedef float f4 __attribute__((ext_vector_type(4)));

__device__ __forceinline__ float fast_sigmoid(float x) {
    return 1.0f / (1.0f + __expf(-x));
}
__device__ __forceinline__ float fast_tanh(float x) {
    float e = __expf(2.0f * x);
    return 1.0f - 2.0f / (e + 1.0f);
}
__device__ __forceinline__ float fma4(float acc, f4 a, f4 b) {
    acc = fmaf(a[0], b[0], acc);
    acc = fmaf(a[1], b[1], acc);
    acc = fmaf(a[2], b[2], acc);
    acc = fmaf(a[3], b[3], acc);
    return acc;
}

#define REP8(M) M(0) M(1) M(2) M(3) M(4) M(5) M(6) M(7)

// One block per batch element, 12 waves = 4 per layer, layers pipelined with
// skew 1 (layer l does t = p - l at phase p). Wave (l, s, uh); lane (kh, jj).
// Each lane: 3 half-rows = 96 weight floats; K-partials reduce via shfl_xor(32).
//
// R3-R9 lesson: the backend REMATERIALIZES invariant weight loads into the
// loop (pressure-reduction default, NOT occupancy-forced: R9 pinned
// waves_per_eu(3,3) + 89KB LDS and still got VGPR=84). That re-streams
// ~294KB/block/phase from L2 = ~3800 cyc/phase = the entire runtime.
// Fix: ONE pre-loop `asm volatile` pass over the weight registers. The asm
// output is a non-rematerializable definition -- every loop use must chain
// from it, so the allocator must keep the weights live (budget 512/3=168
// via waves_per_eu(3,3): fits ~131). R7 proved asm INSIDE the loop instead
// re-feeds the asm with fresh loads each iteration; placement is everything.
__global__
__attribute__((amdgpu_flat_work_group_size(768, 768)))
__attribute__((amdgpu_waves_per_eu(3, 3)))
void gru_pipe(const float* __restrict__ in, float* __restrict__ out,
              const float* __restrict__ Wih, const float* __restrict__ Whh,
              const float* __restrict__ bih, const float* __restrict__ bhh)
{
    const int b   = blockIdx.x;
    const int tid = threadIdx.x;
    const int w   = tid >> 6;        // 0..11
    const int l   = w >> 2;          // layer 0..2
    const int s   = (w >> 1) & 1;    // role
    const int uh  = w & 1;           // unit half
    const int ln  = tid & 63;
    const int kh  = ln >> 5;         // k half
    const int jj  = ln & 31;
    const int j   = uh * 32 + jj;    // hidden unit

    const float* WihL = Wih + (long)l * 192 * 64;
    const float* WhhL = Whh + (long)l * 192 * 64;
    const int gA = s ? 64 + j : j;
    const f4* pa = (const f4*)(WihL + (long)gA * 64 + kh * 32);
    const f4* pb = (const f4*)(WhhL + (long)gA * 64 + kh * 32);
    const f4* pc = (const f4*)((s ? WihL : WhhL) + (long)(128 + j) * 64 + kh * 32);

#define DECLW(k) f4 a##k = pa[k]; f4 b##k = pb[k]; f4 c##k = pc[k];
    REP8(DECLW)
#undef DECLW

    // Sever the load->use remat chain ONCE, before the loop (see header).
#define OPQ(k) asm volatile("" : "+v"(a##k), "+v"(b##k), "+v"(c##k));
    REP8(OPQ)
#undef OPQ

    float bA = 0.0f, bC = 0.0f;
    if (kh == 0) {
        bA = bih[l*192 + gA] + bhh[l*192 + gA];
        bC = s ? bih[l*192 + 128 + j] : bhh[l*192 + 128 + j];
    }

    __shared__ float hbuf[NL][2][Hh];   // per-layer h, double-buffered by parity
    __shared__ float xbuf[2][Hh];       // layer-0 input, double-buffered
    __shared__ float ubuf[NL][Hh];      // r*(Whh_n.h + bhn), s=0 -> s=1
    __shared__ float obuf[2][32][33];   // layer-2 out staging, +1 pad
    __shared__ float ldspad[19456];     // ~76KB pad -> 87KB total: 1 block/CU

    const long ib = (long)b * Hh * Tt;  // [B,H,T]

    if (tid < NL * 2 * Hh) ((float*)hbuf)[tid] = 0.0f;
    float hprev = 0.0f;
    float xcur = 0.0f, xnext = 0.0f;    // wave 8: x prefetch duty
    if (w == 8) {
        xbuf[0][ln] = in[ib + (long)ln * Tt + 0];
        xcur        = in[ib + (long)ln * Tt + 1];
    }
    __syncthreads();

    for (int p = 0; p < Tt + NL - 1; ++p) {
        const int rd = p & 1;
        const int t  = p - l;
        const bool act = (t >= 0) && (t < Tt);

        if (w == 8 && p + 2 < Tt) xnext = in[ib + (long)ln * Tt + (p + 2)];

        float accA = bA, accB = 0.0f, accC = bC;
        float zg = 0.0f;
        if (act) {
            const f4* xs4 = (const f4*)((l == 0) ? xbuf[rd] : hbuf[l - 1][rd]) + kh * 8;
            const f4* hs4 = (const f4*)hbuf[l][rd] + kh * 8;
            if (s == 0) {
#define D0(k) { const f4 xv = xs4[k], hv = hs4[k]; \
                accA = fma4(accA, a##k, xv); \
                accB = fma4(accB, b##k, hv); \
                accC = fma4(accC, c##k, hv); }
                REP8(D0)
#undef D0
            } else {
#define D1(k) { const f4 xv = xs4[k], hv = hs4[k]; \
                accA = fma4(accA, a##k, xv); \
                accB = fma4(accB, b##k, hv); \
                accC = fma4(accC, c##k, xv); }
                REP8(D1)
#undef D1
            }
            accA += __shfl_xor(accA, 32);
            accB += __shfl_xor(accB, 32);
            accC += __shfl_xor(accC, 32);
            const float g = fast_sigmoid(accA + accB);   // r (s=0) or z (s=1)
            if (s == 0) {
                if (kh == 0) ubuf[l][j] = g * accC;      // u = r*(Whh_n.h + bhn)
            }
            zg = g;
        }
        __syncthreads();   // B1: u visible

        if (act && s == 1) {
            const float n = fast_tanh(accC + ubuf[l][j]);   // accC = Wih_n.x + bxn
            const float hnew = fmaf(zg, hprev - n, n);      // (1-z)*n + z*h
            hprev = hnew;
            if (kh == 0) {
                hbuf[l][rd ^ 1][j] = hnew;
                if (l == NL - 1) obuf[uh][jj][t & 31] = hnew;
            }
        }
        if (w == 8) {
            if (p + 1 < Tt) xbuf[rd ^ 1][ln] = xcur;
            xcur = xnext;
        }
        __syncthreads();   // B2: h/x published for next phase

        // Flush staged output every 32 phases (waves 10/11, the obuf writers).
        if ((w >> 1) == 5 && act && (t & 31) == 31) {
            const float* srow = obuf[uh][jj] + kh * 16;
            float4* dst = (float4*)(out + ib + (long)j * Tt + (t - 31) + kh * 16);
            dst[0] = make_float4(srow[0],  srow[1],  srow[2],  srow[3]);
            dst[1] = make_float4(srow[4],  srow[5],  srow[6],  srow[7]);
            dst[2] = make_float4(srow[8],  srow[9],  srow[10], srow[11]);
            dst[3] = make_float4(srow[12], srow[13], srow[14], srow[15]);
        }
    }

    // Keep ldspad ALIVE: write before read. bih ~ (-0.125,0.125) so this never
    // executes at runtime, but the compiler cannot prove it.
    if (bih[0] > 1.0e30f) {
        ldspad[tid] = bih[1];
        ldspad[tid + 4096] = bhh[1];
        __syncthreads();
        out[ib] = ldspad[tid ^ 1] + ldspad[(tid ^ 1) + 4096] + ldspad[tid + 10000];
    }
}

extern "C" void kernel_launch(void* const* d_in, const int* in_sizes, int n_in,
                              void* d_out, int out_size, void* d_ws, size_t ws_size,
                              hipStream_t stream) {
    const float* x   = (const float*)d_in[0];   // [B, H, T]
    const float* Wih = (const float*)d_in[1];   // [3, 192, 64]
    const float* Whh = (const float*)d_in[2];   // [3, 192, 64]
    const float* bih = (const float*)d_in[3];   // [3, 192]
    const float* bhh = (const float*)d_in[4];   // [3, 192]
    float* out = (float*)d_out;                 // [B, H, T]

    gru_pipe<<<Bb, 768, 0, stream>>>(x, out, Wih, Whh, bih, bhh);
}

// Round 11
// 2032.546 us; speedup vs baseline: 1.9125x; 1.4044x over previous
//
#include <hip/hip_runtime.h>

#define Hh 64
#define Tt 2048
#define Bb 256
#define NL 3

typedef _Float16 h2 __attribute__((ext_vector_type(2)));

__device__ __forceinline__ h2 uh2(unsigned u) { union { unsigned u; h2 h; } d; d.u = u; return d.h; }
#define FDOT2(a, b, c) __builtin_amdgcn_fdot2((a), (b), (c), false)

__device__ __forceinline__ float fast_sigmoid(float x) {
    return 1.0f / (1.0f + __expf(-x));
}
__device__ __forceinline__ float fast_tanh(float x) {
    float e = __expf(2.0f * x);
    return 1.0f - 2.0f / (e + 1.0f);
}

#define REPEAT16(M) M(0) M(1) M(2) M(3) M(4) M(5) M(6) M(7) \
                    M(8) M(9) M(10) M(11) M(12) M(13) M(14) M(15)

// ---- prepass 1: fp32 -> fp16 weight convert ----
__global__ void conv_w(const float* __restrict__ src, _Float16* __restrict__ dst, int n) {
    int i = blockIdx.x * 256 + threadIdx.x;
    if (i < n) dst[i] = (_Float16)src[i];
}

// ---- prepass 2: x [B,H,T] fp32 -> xh [B,T,H] fp16 (64x64 LDS tile transpose) ----
__global__ __launch_bounds__(256)
void prep_x(const float* __restrict__ x, _Float16* __restrict__ xh) {
    __shared__ float tile[64][65];
    const int b = blockIdx.x, tc = blockIdx.y;
    const int tt = threadIdx.x & 63, hq = threadIdx.x >> 6;   // tt 0..63, hq 0..3
    const long xb = (long)b * Hh * Tt;
#pragma unroll
    for (int k = 0; k < 16; ++k) {
        const int h = hq * 16 + k;
        tile[h][tt] = x[xb + (long)h * Tt + tc * 64 + tt];    // coalesced along t
    }
    __syncthreads();
    _Float16* dst = xh + ((long)b * Tt + tc * 64 + tt) * Hh + hq * 16;
#pragma unroll
    for (int k = 0; k < 16; ++k) dst[k] = (_Float16)tile[hq * 16 + k][tt];
}

// ---- main: 12 waves/block, 4 per layer, layers pipelined with skew 1 ----
// Wave (l, s, uh); lane (kh, jj). Each lane: 3 half-rows of PACKED f16 weights
// = 48 dwords + ~30 working regs ~= 78, UNDER the backend's hard 84-VGPR
// budget (R4-R10: anything above it gets rematerialized/spilled and re-read
// from L2 at ~295KB/block/phase = the entire 2.9-4.2ms runtime). f16 also
// halves FMA issue (v_dot2_f32_f16, fp32 accumulate) and LDS reads.
__global__
__attribute__((amdgpu_flat_work_group_size(768, 768)))
__attribute__((amdgpu_waves_per_eu(3, 3)))
void gru_pipe(const _Float16* __restrict__ xh, float* __restrict__ out,
              const _Float16* __restrict__ wih16, const _Float16* __restrict__ whh16,
              const float* __restrict__ bih, const float* __restrict__ bhh)
{
    const int b   = blockIdx.x;
    const int tid = threadIdx.x;
    const int w   = tid >> 6;        // 0..11
    const int l   = w >> 2;          // layer 0..2
    const int s   = (w >> 1) & 1;    // role
    const int uh  = w & 1;           // unit half
    const int ln  = tid & 63;
    const int kh  = ln >> 5;         // k half
    const int jj  = ln & 31;
    const int j   = uh * 32 + jj;    // hidden unit

    const int gA = s ? 64 + j : j;
    // h2 element offsets: row*64 f16 = row*32 h2; k-half = kh*16 h2
    const h2* pa = (const h2*)wih16 + ((long)l * 192 + gA) * 32 + kh * 16;
    const h2* pb = (const h2*)whh16 + ((long)l * 192 + gA) * 32 + kh * 16;
    const h2* pc = (const h2*)(s ? wih16 : whh16) + ((long)l * 192 + 128 + j) * 32 + kh * 16;

#define LW(k) h2 A##k = pa[k], B##k = pb[k], C##k = pc[k];
    REPEAT16(LW)
#undef LW
    // Sever the load->use chain once, pre-loop (insurance vs remat; free).
#define OPQ(k) asm volatile("" : "+v"(A##k), "+v"(B##k), "+v"(C##k));
    REPEAT16(OPQ)
#undef OPQ

    float bA = 0.0f, bC = 0.0f;
    if (kh == 0) {
        bA = bih[l*192 + gA] + bhh[l*192 + gA];
        bC = s ? bih[l*192 + 128 + j] : bhh[l*192 + 128 + j];
    }

    __shared__ __align__(16) _Float16 hbuf[NL][2][Hh]; // per-layer h, dbuf by parity
    __shared__ __align__(16) _Float16 xbuf[2][Hh];     // layer-0 input, dbuf
    __shared__ float ubuf[NL][Hh];                     // r*(Whh_n.h + bhn), fp32
    __shared__ float obuf[2][32][33];                  // layer-2 out staging, +1 pad

    const long ib  = (long)b * Hh * Tt;   // [B,H,T] out base
    const long ibh = (long)b * Tt * Hh;   // [B,T,H] xh base

    if (tid < NL * 2 * Hh) ((_Float16*)hbuf)[tid] = (_Float16)0.0f;
    float hprev = 0.0f;
    _Float16 xcur = (_Float16)0.0f, xnext = (_Float16)0.0f;  // wave 8 duty
    if (w == 8) {
        xbuf[0][ln] = xh[ibh + 0 * Hh + ln];
        xcur        = xh[ibh + 1 * Hh + ln];
    }
    __syncthreads();

    // loop-invariant LDS base pointers per parity (uniform broadcast reads)
    const uint4* xsA = (const uint4*)((l == 0) ? xbuf[0] : hbuf[l - 1][0]) + kh * 4;
    const uint4* xsB = (const uint4*)((l == 0) ? xbuf[1] : hbuf[l - 1][1]) + kh * 4;
    const uint4* hsA = (const uint4*)hbuf[l][0] + kh * 4;
    const uint4* hsB = (const uint4*)hbuf[l][1] + kh * 4;

    for (int p = 0; p < Tt + NL - 1; ++p) {
        const int rd = p & 1;
        const int t  = p - l;
        const bool act = (t >= 0) && (t < Tt);

        if (w == 8 && p + 2 < Tt) xnext = xh[ibh + (long)(p + 2) * Hh + ln];

        float accA = bA, accB = 0.0f, accC = bC;
        float zg = 0.0f;
        if (act) {
            const uint4* xs4 = rd ? xsB : xsA;
            const uint4* hs4 = rd ? hsB : hsA;
            // One quad (16B x, 16B h) at a time keeps live pressure ~8 regs.
#define QSTEP(q, k0, k1, k2, k3, S3)  { \
    const uint4 X = xs4[q]; const uint4 Hv = hs4[q]; \
    accA = FDOT2(A##k0, uh2(X.x), accA); accB = FDOT2(B##k0, uh2(Hv.x), accB); accC = FDOT2(C##k0, uh2(S3.x), accC); \
    accA = FDOT2(A##k1, uh2(X.y), accA); accB = FDOT2(B##k1, uh2(Hv.y), accB); accC = FDOT2(C##k1, uh2(S3.y), accC); \
    accA = FDOT2(A##k2, uh2(X.z), accA); accB = FDOT2(B##k2, uh2(Hv.z), accB); accC = FDOT2(C##k2, uh2(S3.z), accC); \
    accA = FDOT2(A##k3, uh2(X.w), accA); accB = FDOT2(B##k3, uh2(Hv.w), accB); accC = FDOT2(C##k3, uh2(S3.w), accC); }
            if (s == 0) {
                QSTEP(0,  0,  1,  2,  3, Hv)
                QSTEP(1,  4,  5,  6,  7, Hv)
                QSTEP(2,  8,  9, 10, 11, Hv)
                QSTEP(3, 12, 13, 14, 15, Hv)
            } else {
                QSTEP(0,  0,  1,  2,  3, X)
                QSTEP(1,  4,  5,  6,  7, X)
                QSTEP(2,  8,  9, 10, 11, X)
                QSTEP(3, 12, 13, 14, 15, X)
            }
#undef QSTEP
            accA += __shfl_xor(accA, 32);
            accB += __shfl_xor(accB, 32);
            accC += __shfl_xor(accC, 32);
            const float g = fast_sigmoid(accA + accB);   // r (s=0) or z (s=1)
            if (s == 0) {
                if (kh == 0) ubuf[l][j] = g * accC;      // u = r*(Whh_n.h + bhn)
            }
            zg = g;
        }
        __syncthreads();   // B1: u visible

        if (act && s == 1) {
            const float n = fast_tanh(accC + ubuf[l][j]);   // accC = Wih_n.x + bxn
            const float hnew = fmaf(zg, hprev - n, n);      // (1-z)*n + z*h
            hprev = hnew;
            if (kh == 0) {
                hbuf[l][rd ^ 1][j] = (_Float16)hnew;
                if (l == NL - 1) obuf[uh][jj][t & 31] = hnew;
            }
        }
        if (w == 8) {
            if (p + 1 < Tt) xbuf[rd ^ 1][ln] = xcur;
            xcur = xnext;
        }
        __syncthreads();   // B2: h/x published for next phase

        // Flush staged output every 32 phases (waves 10/11, the obuf writers).
        if ((w >> 1) == 5 && act && (t & 31) == 31) {
            const float* srow = obuf[uh][jj] + kh * 16;
            float4* dst = (float4*)(out + ib + (long)j * Tt + (t - 31) + kh * 16);
            dst[0] = make_float4(srow[0],  srow[1],  srow[2],  srow[3]);
            dst[1] = make_float4(srow[4],  srow[5],  srow[6],  srow[7]);
            dst[2] = make_float4(srow[8],  srow[9],  srow[10], srow[11]);
            dst[3] = make_float4(srow[12], srow[13], srow[14], srow[15]);
        }
    }
}

extern "C" void kernel_launch(void* const* d_in, const int* in_sizes, int n_in,
                              void* d_out, int out_size, void* d_ws, size_t ws_size,
                              hipStream_t stream) {
    const float* x   = (const float*)d_in[0];   // [B, H, T]
    const float* Wih = (const float*)d_in[1];   // [3, 192, 64]
    const float* Whh = (const float*)d_in[2];   // [3, 192, 64]
    const float* bih = (const float*)d_in[3];   // [3, 192]
    const float* bhh = (const float*)d_in[4];   // [3, 192]
    float* out = (float*)d_out;                 // [B, H, T]

    // ws layout: xh [256][2048][64] f16 (67108864 B) | wih16 (73728 B) | whh16
    _Float16* xh    = (_Float16*)d_ws;
    _Float16* wih16 = (_Float16*)((char*)d_ws + 67108864);
    _Float16* whh16 = (_Float16*)((char*)d_ws + 67108864 + 73728);
    const int nW = NL * 192 * 64;  // 36864

    conv_w<<<(nW + 255) / 256, 256, 0, stream>>>(Wih, wih16, nW);
    conv_w<<<(nW + 255) / 256, 256, 0, stream>>>(Whh, whh16, nW);
    prep_x<<<dim3(Bb, Tt / 64), 256, 0, stream>>>(x, xh);
    gru_pipe<<<Bb, 768, 0, stream>>>(xh, out, wih16, whh16, bih, bhh);
}

// Round 12
// 2027.362 us; speedup vs baseline: 1.9173x; 1.0026x over previous
//
#include <hip/hip_runtime.h>

#define Hh 64
#define Tt 2048
#define Bb 256
#define NL 3

typedef _Float16 h2 __attribute__((ext_vector_type(2)));

__device__ __forceinline__ h2 uh2(unsigned u) { union { unsigned u; h2 h; } d; d.u = u; return d.h; }
#define FDOT2(a, b, c) __builtin_amdgcn_fdot2((a), (b), (c), false)

__device__ __forceinline__ float fast_sigmoid(float x) {
    return 1.0f / (1.0f + __expf(-x));
}
__device__ __forceinline__ float fast_tanh(float x) {
    float e = __expf(2.0f * x);
    return 1.0f - 2.0f / (e + 1.0f);
}

#define REPEAT16(M) M(0) M(1) M(2) M(3) M(4) M(5) M(6) M(7) \
                    M(8) M(9) M(10) M(11) M(12) M(13) M(14) M(15)

// ---- prepass 1: fp32 -> fp16 weight convert ----
__global__ void conv_w(const float* __restrict__ src, _Float16* __restrict__ dst, int n) {
    int i = blockIdx.x * 256 + threadIdx.x;
    if (i < n) dst[i] = (_Float16)src[i];
}

// ---- prepass 2: x [B,H,T] fp32 -> xh [B,T,H] fp16 (64x64 LDS tile transpose) ----
__global__ __launch_bounds__(256)
void prep_x(const float* __restrict__ x, _Float16* __restrict__ xh) {
    __shared__ float tile[64][65];
    const int b = blockIdx.x, tc = blockIdx.y;
    const int tt = threadIdx.x & 63, hq = threadIdx.x >> 6;
    const long xb = (long)b * Hh * Tt;
#pragma unroll
    for (int k = 0; k < 16; ++k) {
        const int h = hq * 16 + k;
        tile[h][tt] = x[xb + (long)h * Tt + tc * 64 + tt];
    }
    __syncthreads();
    _Float16* dst = xh + ((long)b * Tt + tc * 64 + tt) * Hh + hq * 16;
#pragma unroll
    for (int k = 0; k < 16; ++k) dst[k] = (_Float16)tile[hq * 16 + k][tt];
}

// ---- main: 12 waves/block, 4 per layer, layers pipelined with skew 1 ----
// Wave (l, s, uh); lane (kh, jj). Each lane: 3 half-rows of packed f16 = 48
// dwords + ~30 working regs.
//
// R7/R10/R11 post-mortem: asm volatile("" : "+v"(w)) does NOT pin — the
// empty body + TIED constraint folds to zero instructions and the register
// coalescer merges in/out vregs, so the loop uses' reaching def is again the
// invariant global load, which the RA happily REMATERIALIZES into the loop
// (147KB/block/phase restreamed from L2 = the entire runtime, all rounds
// R3-R11). Fix: a real v_mov_b32 in volatile asm with EARLY-CLOBBER output
// ("=&v") and distinct input. The weights' loop-visible def becomes the
// INLINEASM itself: not rematerializable, not coalescable, not sinkable.
// Keeping 78 regs live is now the allocator's cheapest option.
__global__
__attribute__((amdgpu_flat_work_group_size(768, 768)))
__attribute__((amdgpu_waves_per_eu(3, 3)))
void gru_pipe(const _Float16* __restrict__ xh, float* __restrict__ out,
              const _Float16* __restrict__ wih16, const _Float16* __restrict__ whh16,
              const float* __restrict__ bih, const float* __restrict__ bhh)
{
    const int b   = blockIdx.x;
    const int tid = threadIdx.x;
    const int w   = tid >> 6;        // 0..11
    const int l   = w >> 2;          // layer 0..2
    const int s   = (w >> 1) & 1;    // role
    const int uh  = w & 1;           // unit half
    const int ln  = tid & 63;
    const int kh  = ln >> 5;         // k half
    const int jj  = ln & 31;
    const int j   = uh * 32 + jj;    // hidden unit

    const int gA = s ? 64 + j : j;
    const h2* pa = (const h2*)wih16 + ((long)l * 192 + gA) * 32 + kh * 16;
    const h2* pb = (const h2*)whh16 + ((long)l * 192 + gA) * 32 + kh * 16;
    const h2* pc = (const h2*)(s ? wih16 : whh16) + ((long)l * 192 + 128 + j) * 32 + kh * 16;

#define LW(k) h2 A##k = pa[k], B##k = pb[k], C##k = pc[k];
    REPEAT16(LW)
#undef LW

    // Un-rematerializable, un-coalescable weight definitions (see header).
#define PIN1(V) { h2 t; asm volatile("v_mov_b32 %0, %1" : "=&v"(t) : "v"(V)); V = t; }
#define PIN(k) PIN1(A##k) PIN1(B##k) PIN1(C##k)
    REPEAT16(PIN)
#undef PIN
#undef PIN1

    float bA = 0.0f, bC = 0.0f;
    if (kh == 0) {
        bA = bih[l*192 + gA] + bhh[l*192 + gA];
        bC = s ? bih[l*192 + 128 + j] : bhh[l*192 + 128 + j];
    }

    __shared__ __align__(16) _Float16 hbuf[NL][2][Hh]; // per-layer h, dbuf by parity
    __shared__ __align__(16) _Float16 xbuf[2][Hh];     // layer-0 input, dbuf
    __shared__ float ubuf[NL][Hh];                     // r*(Whh_n.h + bhn), fp32
    __shared__ float obuf[2][32][33];                  // layer-2 out staging, +1 pad

    const long ib  = (long)b * Hh * Tt;   // [B,H,T] out base
    const long ibh = (long)b * Tt * Hh;   // [B,T,H] xh base

    if (tid < NL * 2 * Hh) ((_Float16*)hbuf)[tid] = (_Float16)0.0f;
    float hprev = 0.0f;
    _Float16 xcur = (_Float16)0.0f, xnext = (_Float16)0.0f;  // wave 8 duty
    if (w == 8) {
        xbuf[0][ln] = xh[ibh + 0 * Hh + ln];
        xcur        = xh[ibh + 1 * Hh + ln];
    }
    __syncthreads();

    const uint4* xsA = (const uint4*)((l == 0) ? xbuf[0] : hbuf[l - 1][0]) + kh * 4;
    const uint4* xsB = (const uint4*)((l == 0) ? xbuf[1] : hbuf[l - 1][1]) + kh * 4;
    const uint4* hsA = (const uint4*)hbuf[l][0] + kh * 4;
    const uint4* hsB = (const uint4*)hbuf[l][1] + kh * 4;

    for (int p = 0; p < Tt + NL - 1; ++p) {
        const int rd = p & 1;
        const int t  = p - l;
        const bool act = (t >= 0) && (t < Tt);

        if (w == 8 && p + 2 < Tt) xnext = xh[ibh + (long)(p + 2) * Hh + ln];

        float accA = bA, accB = 0.0f, accC = bC;
        float zg = 0.0f;
        if (act) {
            const uint4* xs4 = rd ? xsB : xsA;
            const uint4* hs4 = rd ? hsB : hsA;
#define QSTEP(q, k0, k1, k2, k3, S3)  { \
    const uint4 X = xs4[q]; const uint4 Hv = hs4[q]; \
    accA = FDOT2(A##k0, uh2(X.x), accA); accB = FDOT2(B##k0, uh2(Hv.x), accB); accC = FDOT2(C##k0, uh2(S3.x), accC); \
    accA = FDOT2(A##k1, uh2(X.y), accA); accB = FDOT2(B##k1, uh2(Hv.y), accB); accC = FDOT2(C##k1, uh2(S3.y), accC); \
    accA = FDOT2(A##k2, uh2(X.z), accA); accB = FDOT2(B##k2, uh2(Hv.z), accB); accC = FDOT2(C##k2, uh2(S3.z), accC); \
    accA = FDOT2(A##k3, uh2(X.w), accA); accB = FDOT2(B##k3, uh2(Hv.w), accB); accC = FDOT2(C##k3, uh2(S3.w), accC); }
            if (s == 0) {
                QSTEP(0,  0,  1,  2,  3, Hv)
                QSTEP(1,  4,  5,  6,  7, Hv)
                QSTEP(2,  8,  9, 10, 11, Hv)
                QSTEP(3, 12, 13, 14, 15, Hv)
            } else {
                QSTEP(0,  0,  1,  2,  3, X)
                QSTEP(1,  4,  5,  6,  7, X)
                QSTEP(2,  8,  9, 10, 11, X)
                QSTEP(3, 12, 13, 14, 15, X)
            }
#undef QSTEP
            accA += __shfl_xor(accA, 32);
            accB += __shfl_xor(accB, 32);
            accC += __shfl_xor(accC, 32);
            const float g = fast_sigmoid(accA + accB);   // r (s=0) or z (s=1)
            if (s == 0) {
                if (kh == 0) ubuf[l][j] = g * accC;      // u = r*(Whh_n.h + bhn)
            }
            zg = g;
        }
        __syncthreads();   // B1: u visible

        if (act && s == 1) {
            const float n = fast_tanh(accC + ubuf[l][j]);   // accC = Wih_n.x + bxn
            const float hnew = fmaf(zg, hprev - n, n);      // (1-z)*n + z*h
            hprev = hnew;
            if (kh == 0) {
                hbuf[l][rd ^ 1][j] = (_Float16)hnew;
                if (l == NL - 1) obuf[uh][jj][t & 31] = hnew;
            }
        }
        if (w == 8) {
            if (p + 1 < Tt) xbuf[rd ^ 1][ln] = xcur;
            xcur = xnext;
        }
        __syncthreads();   // B2: h/x published for next phase

        if ((w >> 1) == 5 && act && (t & 31) == 31) {
            const float* srow = obuf[uh][jj] + kh * 16;
            float4* dst = (float4*)(out + ib + (long)j * Tt + (t - 31) + kh * 16);
            dst[0] = make_float4(srow[0],  srow[1],  srow[2],  srow[3]);
            dst[1] = make_float4(srow[4],  srow[5],  srow[6],  srow[7]);
            dst[2] = make_float4(srow[8],  srow[9],  srow[10], srow[11]);
            dst[3] = make_float4(srow[12], srow[13], srow[14], srow[15]);
        }
    }
}

extern "C" void kernel_launch(void* const* d_in, const int* in_sizes, int n_in,
                              void* d_out, int out_size, void* d_ws, size_t ws_size,
                              hipStream_t stream) {
    const float* x   = (const float*)d_in[0];   // [B, H, T]
    const float* Wih = (const float*)d_in[1];   // [3, 192, 64]
    const float* Whh = (const float*)d_in[2];   // [3, 192, 64]
    const float* bih = (const float*)d_in[3];   // [3, 192]
    const float* bhh = (const float*)d_in[4];   // [3, 192]
    float* out = (float*)d_out;                 // [B, H, T]

    _Float16* xh    = (_Float16*)d_ws;
    _Float16* wih16 = (_Float16*)((char*)d_ws + 67108864);
    _Float16* whh16 = (_Float16*)((char*)d_ws + 67108864 + 73728);
    const int nW = NL * 192 * 64;  // 36864

    conv_w<<<(nW + 255) / 256, 256, 0, stream>>>(Wih, wih16, nW);
    conv_w<<<(nW + 255) / 256, 256, 0, stream>>>(Whh, whh16, nW);
    prep_x<<<dim3(Bb, Tt / 64), 256, 0, stream>>>(x, xh);
    gru_pipe<<<Bb, 768, 0, stream>>>(xh, out, wih16, whh16, bih, bhh);
}